// Round 3
// baseline (1491.258 us; speedup 1.0000x reference)
//
#include <hip/hip_runtime.h>
#include <stddef.h>

#define NBATCH 8
#define NP 4096
#define KNN 20
#define NEGF (-3.402823466e38f)

// ---------------------------------------------------------------------------
// two-level cached wave-wide top-20 (largest val, ties -> smallest j)
// Per lane: val[64] in 8 groups of 8, cached (gv,gt) per group.
// LANEMAJOR: j = lane*64 + t ; else j = t*64 + lane.
// ---------------------------------------------------------------------------
template<int G>
__device__ __forceinline__ void rem_group(float (&val)[64], float (&gv)[8], int (&gt)[8],
                                          int s, bool own) {
  switch (s) {
    case 0: if (own) val[G * 8 + 0] = NEGF; break;
    case 1: if (own) val[G * 8 + 1] = NEGF; break;
    case 2: if (own) val[G * 8 + 2] = NEGF; break;
    case 3: if (own) val[G * 8 + 3] = NEGF; break;
    case 4: if (own) val[G * 8 + 4] = NEGF; break;
    case 5: if (own) val[G * 8 + 5] = NEGF; break;
    case 6: if (own) val[G * 8 + 6] = NEGF; break;
    case 7: if (own) val[G * 8 + 7] = NEGF; break;
  }
  if (own) {
    float mv = val[G * 8]; int mt = G * 8;
    #pragma unroll
    for (int q = 1; q < 8; ++q)
      if (val[G * 8 + q] > mv) { mv = val[G * 8 + q]; mt = G * 8 + q; }
    gv[G] = mv; gt[G] = mt;
  }
}

template<bool LANEMAJOR>
__device__ __forceinline__ void wave_topk(float (&val)[64], float (&gv)[8], int (&gt)[8],
                                          int lane, int rowbase, int* __restrict__ idx_out) {
  float lv = gv[0]; int lt = gt[0];
  #pragma unroll
  for (int g = 1; g < 8; ++g) if (gv[g] > lv) { lv = gv[g]; lt = gt[g]; }
  int myidx = 0;
  #pragma unroll 1
  for (int r = 0; r < KNN; ++r) {
    float mv = lv;
    int mj = LANEMAJOR ? ((lane << 6) | lt) : ((lt << 6) | lane);
    #pragma unroll
    for (int off = 32; off; off >>= 1) {
      float om = __shfl_xor(mv, off, 64);
      int   oj = __shfl_xor(mj, off, 64);
      if (om > mv || (om == mv && oj < mj)) { mv = om; mj = oj; }
    }
    if (lane == r) myidx = mj;
    // mj is wave-uniform after the butterfly -> scalar switch values
    int mju = __builtin_amdgcn_readfirstlane(mj);
    int wl = LANEMAJOR ? (mju >> 6) : (mju & 63);
    int t  = LANEMAJOR ? (mju & 63) : (mju >> 6);
    bool own = (lane == wl);
    switch (t >> 3) {
      case 0: rem_group<0>(val, gv, gt, t & 7, own); break;
      case 1: rem_group<1>(val, gv, gt, t & 7, own); break;
      case 2: rem_group<2>(val, gv, gt, t & 7, own); break;
      case 3: rem_group<3>(val, gv, gt, t & 7, own); break;
      case 4: rem_group<4>(val, gv, gt, t & 7, own); break;
      case 5: rem_group<5>(val, gv, gt, t & 7, own); break;
      case 6: rem_group<6>(val, gv, gt, t & 7, own); break;
      case 7: rem_group<7>(val, gv, gt, t & 7, own); break;
    }
    if (own) {  // removed element was this lane's max: rescan cached group maxes
      lv = gv[0]; lt = gt[0];
      #pragma unroll
      for (int g = 1; g < 8; ++g) if (gv[g] > lv) { lv = gv[g]; lt = gt[g]; }
    }
  }
  if (lane < KNN) idx_out[(size_t)rowbase * KNN + lane] = myidx;
}

// ---------------------------------------------------------------------------
// squared norms of x rows
// ---------------------------------------------------------------------------
__global__ __launch_bounds__(256) void sq_kernel(const float* __restrict__ x,
                                                 float* __restrict__ sqx) {
  int gid = blockIdx.x * 256 + threadIdx.x;  // 0..32767
  float a = x[gid * 3 + 0];
  float b = x[gid * 3 + 1];
  float c = x[gid * 3 + 2];
  sqx[gid] = a * a + b * b + c * c;
}

// ---------------------------------------------------------------------------
// stage-1 knn on xyz; one wave per row; lane-major j = lane*64+t
// ---------------------------------------------------------------------------
__global__ __launch_bounds__(256) void knn1_kernel(const float* __restrict__ x,
                                                   const float* __restrict__ sqx,
                                                   int* __restrict__ idx1) {
  int wave = threadIdx.x >> 6, lane = threadIdx.x & 63;
  int row = blockIdx.x * 4 + wave;      // global row
  int b = row >> 12;                    // /4096
  int i = row & (NP - 1);
  const float* xb = x + (size_t)b * NP * 3;
  float xi0 = xb[i * 3 + 0], xi1 = xb[i * 3 + 1], xi2 = xb[i * 3 + 2];
  float sqi = sqx[row];
  const float* sqb = sqx + b * NP;
  float val[64]; float gv[8]; int gt[8];
  #pragma unroll
  for (int g = 0; g < 8; ++g) {
    #pragma unroll
    for (int s = 0; s < 8; ++s) {
      int t = g * 8 + s;
      int j = (lane << 6) | t;
      float a0 = xb[j * 3 + 0], a1 = xb[j * 3 + 1], a2 = xb[j * 3 + 2];
      float dot = xi0 * a0 + xi1 * a1 + xi2 * a2;
      val[t] = 2.f * dot - sqi - sqb[j];
    }
    float mv = val[g * 8]; int mt = g * 8;
    #pragma unroll
    for (int s = 1; s < 8; ++s)
      if (val[g * 8 + s] > mv) { mv = val[g * 8 + s]; mt = g * 8 + s; }
    gv[g] = mv; gt[g] = mt;
  }
  wave_topk<true>(val, gv, gt, lane, row, idx1);
}

// ---------------------------------------------------------------------------
// F1[j] = mlp1(x[0,j])  (3->64 relu ->64 relu ->64), one wave per row
// ---------------------------------------------------------------------------
__global__ __launch_bounds__(256) void mlp1_kernel(const float* __restrict__ x,
                                                   const float* __restrict__ w1, const float* __restrict__ b1,
                                                   const float* __restrict__ w2, const float* __restrict__ b2,
                                                   const float* __restrict__ w3, const float* __restrict__ b3,
                                                   float* __restrict__ F1) {
  int wave = threadIdx.x >> 6, lane = threadIdx.x & 63;
  int j = blockIdx.x * 4 + wave;        // 0..4095 (batch 0 rows)
  float x0 = x[j * 3 + 0], x1 = x[j * 3 + 1], x2 = x[j * 3 + 2];
  float h1 = fmaf(x2, w1[128 + lane], fmaf(x1, w1[64 + lane], fmaf(x0, w1[lane], b1[lane])));
  h1 = fmaxf(h1, 0.f);
  float acc = b2[lane];
  #pragma unroll
  for (int c = 0; c < 64; ++c) acc = fmaf(__shfl(h1, c, 64), w2[c * 64 + lane], acc);
  float h2 = fmaxf(acc, 0.f);
  acc = b3[lane];
  #pragma unroll
  for (int c = 0; c < 64; ++c) acc = fmaf(__shfl(h2, c, 64), w3[c * 64 + lane], acc);
  F1[j * 64 + lane] = acc;
}

// ---------------------------------------------------------------------------
// h[row] = max_k F1[idx1[row,k]] ; sqh[row] = ||h[row]||^2
// ---------------------------------------------------------------------------
__global__ __launch_bounds__(256) void pool1_kernel(const float* __restrict__ F1,
                                                    const int* __restrict__ idx1,
                                                    float* __restrict__ h,
                                                    float* __restrict__ sqh) {
  int wave = threadIdx.x >> 6, lane = threadIdx.x & 63;
  int row = blockIdx.x * 4 + wave;
  float m = NEGF;
  #pragma unroll
  for (int k = 0; k < KNN; ++k) {
    int jj = idx1[(size_t)row * KNN + k];
    m = fmaxf(m, F1[jj * 64 + lane]);
  }
  h[(size_t)row * 64 + lane] = m;
  float s = m * m;
  #pragma unroll
  for (int off = 32; off; off >>= 1) s += __shfl_xor(s, off, 64);
  if (lane == 0) sqh[row] = s;
}

// ---------------------------------------------------------------------------
// pd[i][j] = 2*h_i.h_j - sq_i - sq_j for one batch (4096x4096x64 f32 GEMM)
// ---------------------------------------------------------------------------
__device__ __forceinline__ int swz(int g, int r) { return g ^ ((r & 15) ^ ((r >> 4) & 3)); }

__global__ __launch_bounds__(256) void pd_gemm_kernel(const float* __restrict__ h,
                                                      const float* __restrict__ sqh,
                                                      float* __restrict__ pd, int b) {
  __shared__ float As[64 * 64];
  __shared__ float Bs[64 * 64];
  const int it = blockIdx.x >> 6;
  const int jt = blockIdx.x & 63;
  const int i0 = it * 64, j0 = jt * 64;
  const float* hb = h + (size_t)b * NP * 64;
  const int tid = threadIdx.x;
  #pragma unroll
  for (int s = 0; s < 4; ++s) {
    int f4 = tid + s * 256;
    int r = f4 >> 4, g = f4 & 15;
    int gs = swz(g, r);
    float4 va = *reinterpret_cast<const float4*>(&hb[(size_t)(i0 + r) * 64 + g * 4]);
    *reinterpret_cast<float4*>(&As[r * 64 + gs * 4]) = va;
    float4 vb = *reinterpret_cast<const float4*>(&hb[(size_t)(j0 + r) * 64 + g * 4]);
    *reinterpret_cast<float4*>(&Bs[r * 64 + gs * 4]) = vb;
  }
  __syncthreads();
  const int tx = tid & 15, ty = tid >> 4;
  float acc[4][4] = {};
  #pragma unroll
  for (int c = 0; c < 64; c += 4) {
    int g = c >> 2;
    float4 a[4], bb[4];
    #pragma unroll
    for (int q = 0; q < 4; ++q) {
      int r = ty * 4 + q;
      a[q] = *reinterpret_cast<const float4*>(&As[r * 64 + (swz(g, r) << 2)]);
    }
    #pragma unroll
    for (int p = 0; p < 4; ++p) {
      int r = tx * 4 + p;
      bb[p] = *reinterpret_cast<const float4*>(&Bs[r * 64 + (swz(g, r) << 2)]);
    }
    #pragma unroll
    for (int q = 0; q < 4; ++q) {
      #pragma unroll
      for (int p = 0; p < 4; ++p) {
        acc[q][p] = fmaf(a[q].x, bb[p].x, acc[q][p]);
        acc[q][p] = fmaf(a[q].y, bb[p].y, acc[q][p]);
        acc[q][p] = fmaf(a[q].z, bb[p].z, acc[q][p]);
        acc[q][p] = fmaf(a[q].w, bb[p].w, acc[q][p]);
      }
    }
  }
  const float* sq = sqh + b * NP;
  float sj0 = sq[j0 + tx * 4 + 0];
  float sj1 = sq[j0 + tx * 4 + 1];
  float sj2 = sq[j0 + tx * 4 + 2];
  float sj3 = sq[j0 + tx * 4 + 3];
  #pragma unroll
  for (int q = 0; q < 4; ++q) {
    int i = i0 + ty * 4 + q;
    float sqi = sq[i];
    float4 o;
    o.x = 2.f * acc[q][0] - sqi - sj0;
    o.y = 2.f * acc[q][1] - sqi - sj1;
    o.z = 2.f * acc[q][2] - sqi - sj2;
    o.w = 2.f * acc[q][3] - sqi - sj3;
    *reinterpret_cast<float4*>(&pd[(size_t)i * NP + j0 + tx * 4]) = o;
  }
}

// ---------------------------------------------------------------------------
// top-20 from materialized pd rows (one batch); lane-major j -> float4 loads
// ---------------------------------------------------------------------------
__global__ __launch_bounds__(256) void knn_select_kernel(const float* __restrict__ pd,
                                                         int* __restrict__ idx2, int b) {
  int wave = threadIdx.x >> 6, lane = threadIdx.x & 63;
  int row = blockIdx.x * 4 + wave;      // local row in batch
  const float* prow = pd + (size_t)row * NP + (lane << 6);
  float val[64]; float gv[8]; int gt[8];
  #pragma unroll
  for (int g = 0; g < 8; ++g) {
    float4 v0 = *reinterpret_cast<const float4*>(&prow[g * 8]);
    float4 v1 = *reinterpret_cast<const float4*>(&prow[g * 8 + 4]);
    val[g * 8 + 0] = v0.x; val[g * 8 + 1] = v0.y; val[g * 8 + 2] = v0.z; val[g * 8 + 3] = v0.w;
    val[g * 8 + 4] = v1.x; val[g * 8 + 5] = v1.y; val[g * 8 + 6] = v1.z; val[g * 8 + 7] = v1.w;
    float mv = val[g * 8]; int mt = g * 8;
    #pragma unroll
    for (int s = 1; s < 8; ++s)
      if (val[g * 8 + s] > mv) { mv = val[g * 8 + s]; mt = g * 8 + s; }
    gv[g] = mv; gt[g] = mt;
  }
  wave_topk<true>(val, gv, gt, lane, b * NP + row, idx2);
}

// ---------------------------------------------------------------------------
// fallback fused knn2 (no pd buffer): 8 rows/block, LDS-staged j tiles
// j = t*64 + lane (t-major)
// ---------------------------------------------------------------------------
__global__ __launch_bounds__(512) void knn2_fused_kernel(const float* __restrict__ h,
                                                         const float* __restrict__ sqh,
                                                         int* __restrict__ idx2) {
  __shared__ float tile[64 * 64];
  const int wave = threadIdx.x >> 6, lane = threadIdx.x & 63;
  const int row = blockIdx.x * 8 + wave;
  const int b = row >> 12;
  const int jb = b * NP;
  float hi[64];
  #pragma unroll
  for (int q2 = 0; q2 < 16; ++q2) {
    float4 v = *reinterpret_cast<const float4*>(&h[(size_t)row * 64 + q2 * 4]);
    hi[q2 * 4 + 0] = v.x; hi[q2 * 4 + 1] = v.y; hi[q2 * 4 + 2] = v.z; hi[q2 * 4 + 3] = v.w;
  }
  float sqi = sqh[row];
  float val[64];
  #pragma unroll
  for (int tt = 0; tt < 64; ++tt) {
    __syncthreads();
    #pragma unroll
    for (int s = 0; s < 2; ++s) {
      int f4 = threadIdx.x + s * 512;
      int jj = f4 >> 4, g = f4 & 15;
      float4 v = *reinterpret_cast<const float4*>(&h[(size_t)(jb + tt * 64 + jj) * 64 + g * 4]);
      int gs = g ^ (jj & 15);
      *reinterpret_cast<float4*>(&tile[jj * 64 + gs * 4]) = v;
    }
    __syncthreads();
    float acc = 0.f;
    #pragma unroll
    for (int g = 0; g < 16; ++g) {
      int gs = g ^ (lane & 15);
      float4 v = *reinterpret_cast<const float4*>(&tile[lane * 64 + gs * 4]);
      acc = fmaf(hi[4 * g + 0], v.x, acc);
      acc = fmaf(hi[4 * g + 1], v.y, acc);
      acc = fmaf(hi[4 * g + 2], v.z, acc);
      acc = fmaf(hi[4 * g + 3], v.w, acc);
    }
    val[tt] = 2.f * acc - sqi - sqh[jb + tt * 64 + lane];
  }
  float gv[8]; int gt[8];
  #pragma unroll
  for (int g = 0; g < 8; ++g) {
    float mv = val[g * 8]; int mt = g * 8;
    #pragma unroll
    for (int s = 1; s < 8; ++s)
      if (val[g * 8 + s] > mv) { mv = val[g * 8 + s]; mt = g * 8 + s; }
    gv[g] = mv; gt[g] = mt;
  }
  wave_topk<false>(val, gv, gt, lane, row, idx2);
}

// ---------------------------------------------------------------------------
// G4[j] = h[0,j] @ w4 + b4  (64 -> 128)
// ---------------------------------------------------------------------------
__global__ __launch_bounds__(128) void g4_kernel(const float* __restrict__ h,
                                                 const float* __restrict__ w4,
                                                 const float* __restrict__ b4,
                                                 float* __restrict__ G4) {
  __shared__ float hj[64];
  int j = blockIdx.x;
  int o = threadIdx.x;
  if (o < 64) hj[o] = h[(size_t)j * 64 + o];
  __syncthreads();
  float acc = b4[o];
  #pragma unroll
  for (int c = 0; c < 64; ++c) acc = fmaf(hj[c], w4[c * 128 + o], acc);
  G4[(size_t)j * 128 + o] = acc;
}

// ---------------------------------------------------------------------------
// h2[row] = max_k G4[idx2[row,k]]
// ---------------------------------------------------------------------------
__global__ __launch_bounds__(256) void pool2_kernel(const float* __restrict__ G4,
                                                    const int* __restrict__ idx2,
                                                    float* __restrict__ h2) {
  int gid = blockIdx.x * 256 + threadIdx.x;
  int row = gid >> 7, o = gid & 127;
  float m = NEGF;
  #pragma unroll
  for (int k = 0; k < KNN; ++k) {
    int jj = idx2[(size_t)row * KNN + k];
    m = fmaxf(m, G4[(size_t)jj * 128 + o]);
  }
  h2[(size_t)gid] = m;
}

// ---------------------------------------------------------------------------
// out = h2 @ w5 + b5  (32768 x 1024 x 128), 64x64 tile, 4x4/thread
// ---------------------------------------------------------------------------
__global__ __launch_bounds__(256) void final_gemm_kernel(const float* __restrict__ h2,
                                                         const float* __restrict__ w5,
                                                         const float* __restrict__ b5,
                                                         float* __restrict__ out) {
  __shared__ float As[64 * 128];
  __shared__ float Bs[128 * 64];
  const int mt = blockIdx.x >> 4;
  const int nt = blockIdx.x & 15;
  const int row0 = mt * 64, col0 = nt * 64;
  const int tid = threadIdx.x;
  #pragma unroll
  for (int s = 0; s < 8; ++s) {
    int f4 = tid + s * 256;
    int i = f4 >> 5, kf = f4 & 31;
    float4 v = *reinterpret_cast<const float4*>(&h2[(size_t)(row0 + i) * 128 + kf * 4]);
    *reinterpret_cast<float4*>(&As[i * 128 + kf * 4]) = v;
  }
  #pragma unroll
  for (int s = 0; s < 8; ++s) {
    int f4 = tid + s * 256;
    int k = f4 >> 4, g = f4 & 15;
    float4 v = *reinterpret_cast<const float4*>(&w5[(size_t)k * 1024 + col0 + g * 4]);
    *reinterpret_cast<float4*>(&Bs[k * 64 + g * 4]) = v;
  }
  __syncthreads();
  const int tx = tid & 15, ty = tid >> 4;
  float acc[4][4] = {};
  #pragma unroll
  for (int k = 0; k < 128; k += 4) {
    float4 a[4], bb[4];
    #pragma unroll
    for (int q = 0; q < 4; ++q)
      a[q] = *reinterpret_cast<const float4*>(&As[(ty * 4 + q) * 128 + k]);
    #pragma unroll
    for (int kk = 0; kk < 4; ++kk)
      bb[kk] = *reinterpret_cast<const float4*>(&Bs[(k + kk) * 64 + tx * 4]);
    #pragma unroll
    for (int q = 0; q < 4; ++q) {
      acc[q][0] = fmaf(a[q].w, bb[3].x, fmaf(a[q].z, bb[2].x, fmaf(a[q].y, bb[1].x, fmaf(a[q].x, bb[0].x, acc[q][0]))));
      acc[q][1] = fmaf(a[q].w, bb[3].y, fmaf(a[q].z, bb[2].y, fmaf(a[q].y, bb[1].y, fmaf(a[q].x, bb[0].y, acc[q][1]))));
      acc[q][2] = fmaf(a[q].w, bb[3].z, fmaf(a[q].z, bb[2].z, fmaf(a[q].y, bb[1].z, fmaf(a[q].x, bb[0].z, acc[q][2]))));
      acc[q][3] = fmaf(a[q].w, bb[3].w, fmaf(a[q].z, bb[2].w, fmaf(a[q].y, bb[1].w, fmaf(a[q].x, bb[0].w, acc[q][3]))));
    }
  }
  float b0 = b5[col0 + tx * 4 + 0];
  float b1 = b5[col0 + tx * 4 + 1];
  float b2 = b5[col0 + tx * 4 + 2];
  float b3 = b5[col0 + tx * 4 + 3];
  #pragma unroll
  for (int q = 0; q < 4; ++q) {
    float4 o;
    o.x = acc[q][0] + b0;
    o.y = acc[q][1] + b1;
    o.z = acc[q][2] + b2;
    o.w = acc[q][3] + b3;
    *reinterpret_cast<float4*>(&out[(size_t)(row0 + ty * 4 + q) * 1024 + col0 + tx * 4]) = o;
  }
}

// ---------------------------------------------------------------------------
extern "C" void kernel_launch(void* const* d_in, const int* in_sizes, int n_in,
                              void* d_out, int out_size, void* d_ws, size_t ws_size,
                              hipStream_t stream) {
  const float* x  = (const float*)d_in[0];
  const float* w1 = (const float*)d_in[1];
  const float* b1 = (const float*)d_in[2];
  const float* w2 = (const float*)d_in[3];
  const float* b2 = (const float*)d_in[4];
  const float* w3 = (const float*)d_in[5];
  const float* b3 = (const float*)d_in[6];
  const float* w4 = (const float*)d_in[7];
  const float* b4 = (const float*)d_in[8];
  const float* w5 = (const float*)d_in[9];
  const float* b5 = (const float*)d_in[10];
  float* out = (float*)d_out;
  char* ws = (char*)d_ws;

  // layout (bytes)
  float* h    = (float*)(ws + 0);                       //  8,388,608
  float* sqh  = (float*)(ws + 8388608);                 //    131,072
  int*   idx2 = (int*)  (ws + 8519680);                 //  2,621,440
  char*  X    = ws + 11141120;                          // overlay region
  float* sqx  = (float*)(X + 0);                        //    131,072 (dead after knn1)
  int*   idx1 = (int*)  (X + 131072);                   //  2,621,440 (dead after pool1)
  float* F1   = (float*)(X + 2752512);                  //  1,048,576 (dead after pool1)
  float* pd   = (float*)(X + 0);                        // 67,108,864 (live only during knn2 fast path)
  float* G4   = (float*)(X + 0);                        //  2,097,152 (after knn2)
  float* h2   = (float*)(X + 2097152);                  // 16,777,216 (after knn2)

  const size_t NEED_FAST = 11141120 + 67108864;

  sq_kernel<<<128, 256, 0, stream>>>(x, sqx);
  knn1_kernel<<<8192, 256, 0, stream>>>(x, sqx, idx1);
  mlp1_kernel<<<1024, 256, 0, stream>>>(x, w1, b1, w2, b2, w3, b3, F1);
  pool1_kernel<<<8192, 256, 0, stream>>>(F1, idx1, h, sqh);

  if (ws_size >= NEED_FAST) {
    for (int b = 0; b < NBATCH; ++b) {
      pd_gemm_kernel<<<4096, 256, 0, stream>>>(h, sqh, pd, b);
      knn_select_kernel<<<1024, 256, 0, stream>>>(pd, idx2, b);
    }
  } else {
    knn2_fused_kernel<<<4096, 512, 0, stream>>>(h, sqh, idx2);
  }

  g4_kernel<<<4096, 128, 0, stream>>>(h, w4, b4, G4);
  pool2_kernel<<<16384, 256, 0, stream>>>(G4, idx2, h2);
  final_gemm_kernel<<<8192, 256, 0, stream>>>(h2, w5, b5, out);
}

// Round 4
// 1181.971 us; speedup vs baseline: 1.2617x; 1.2617x over previous
//
#include <hip/hip_runtime.h>
#include <stddef.h>

#define NBATCH 8
#define NP 4096
#define KNN 20
#define NEGF (-3.402823466e38f)

// ===========================================================================
// Spill-free wave top-20: per lane only named scalars (gv0..7/gt0..7 group
// maxes, 64-bit removal mask rm0/rm1, running lv/lt). Owner lane recomputes
// its 8-candidate group on removal. j = lane*64 + t (lane-major).
// ===========================================================================

// ---- group-max for knn1: recompute 8 distances from x (scores = 2*dot - sqj;
//      the -sqi term is constant per row and dropped: selection-invariant) ----
template<int G>
__device__ __forceinline__ void knn1_group(const float* __restrict__ xb,
                                           const float* __restrict__ sqb,
                                           int lane, float xi0, float xi1, float xi2,
                                           unsigned mask8, float& gmv, int& gmt) {
  const float* xg = xb + 3 * ((lane << 6) | (G * 8));
  const float* sg = sqb + ((lane << 6) | (G * 8));
  float4 v0 = *(const float4*)(xg + 0);
  float4 v1 = *(const float4*)(xg + 4);
  float4 v2 = *(const float4*)(xg + 8);
  float4 v3 = *(const float4*)(xg + 12);
  float4 v4 = *(const float4*)(xg + 16);
  float4 v5 = *(const float4*)(xg + 20);
  float4 s0 = *(const float4*)(sg + 0);
  float4 s1 = *(const float4*)(sg + 4);
  float d0 = fmaf(xi2, v0.z, fmaf(xi1, v0.y, xi0 * v0.x)); d0 = fmaf(d0, 2.f, -s0.x);
  float d1 = fmaf(xi2, v1.y, fmaf(xi1, v1.x, xi0 * v0.w)); d1 = fmaf(d1, 2.f, -s0.y);
  float d2 = fmaf(xi2, v2.x, fmaf(xi1, v1.w, xi0 * v1.z)); d2 = fmaf(d2, 2.f, -s0.z);
  float d3 = fmaf(xi2, v2.w, fmaf(xi1, v2.z, xi0 * v2.y)); d3 = fmaf(d3, 2.f, -s0.w);
  float d4 = fmaf(xi2, v3.z, fmaf(xi1, v3.y, xi0 * v3.x)); d4 = fmaf(d4, 2.f, -s1.x);
  float d5 = fmaf(xi2, v4.y, fmaf(xi1, v4.x, xi0 * v3.w)); d5 = fmaf(d5, 2.f, -s1.y);
  float d6 = fmaf(xi2, v5.x, fmaf(xi1, v4.w, xi0 * v4.z)); d6 = fmaf(d6, 2.f, -s1.z);
  float d7 = fmaf(xi2, v5.w, fmaf(xi1, v5.z, xi0 * v5.y)); d7 = fmaf(d7, 2.f, -s1.w);
  if (mask8 & 1u)   d0 = NEGF;
  if (mask8 & 2u)   d1 = NEGF;
  if (mask8 & 4u)   d2 = NEGF;
  if (mask8 & 8u)   d3 = NEGF;
  if (mask8 & 16u)  d4 = NEGF;
  if (mask8 & 32u)  d5 = NEGF;
  if (mask8 & 64u)  d6 = NEGF;
  if (mask8 & 128u) d7 = NEGF;
  float mv = d0; int mt = 0;
  if (d1 > mv) { mv = d1; mt = 1; }
  if (d2 > mv) { mv = d2; mt = 2; }
  if (d3 > mv) { mv = d3; mt = 3; }
  if (d4 > mv) { mv = d4; mt = 4; }
  if (d5 > mv) { mv = d5; mt = 5; }
  if (d6 > mv) { mv = d6; mt = 6; }
  if (d7 > mv) { mv = d7; mt = 7; }
  gmv = mv; gmt = G * 8 + mt;
}

// ---- group-max for knn_select: reload 8 pd values ----
template<int G>
__device__ __forceinline__ void sel_group(const float* __restrict__ prow,
                                          unsigned mask8, float& gmv, int& gmt) {
  float4 a = *(const float4*)(prow + G * 8);
  float4 b = *(const float4*)(prow + G * 8 + 4);
  float d0 = a.x, d1 = a.y, d2 = a.z, d3 = a.w;
  float d4 = b.x, d5 = b.y, d6 = b.z, d7 = b.w;
  if (mask8 & 1u)   d0 = NEGF;
  if (mask8 & 2u)   d1 = NEGF;
  if (mask8 & 4u)   d2 = NEGF;
  if (mask8 & 8u)   d3 = NEGF;
  if (mask8 & 16u)  d4 = NEGF;
  if (mask8 & 32u)  d5 = NEGF;
  if (mask8 & 64u)  d6 = NEGF;
  if (mask8 & 128u) d7 = NEGF;
  float mv = d0; int mt = 0;
  if (d1 > mv) { mv = d1; mt = 1; }
  if (d2 > mv) { mv = d2; mt = 2; }
  if (d3 > mv) { mv = d3; mt = 3; }
  if (d4 > mv) { mv = d4; mt = 4; }
  if (d5 > mv) { mv = d5; mt = 5; }
  if (d6 > mv) { mv = d6; mt = 6; }
  if (d7 > mv) { mv = d7; mt = 7; }
  gmv = mv; gmt = G * 8 + mt;
}

#define LANE_SCAN()                                            \
  lv = gv0; lt = gt0;                                          \
  if (gv1 > lv) { lv = gv1; lt = gt1; }                        \
  if (gv2 > lv) { lv = gv2; lt = gt2; }                        \
  if (gv3 > lv) { lv = gv3; lt = gt3; }                        \
  if (gv4 > lv) { lv = gv4; lt = gt4; }                        \
  if (gv5 > lv) { lv = gv5; lt = gt5; }                        \
  if (gv6 > lv) { lv = gv6; lt = gt6; }                        \
  if (gv7 > lv) { lv = gv7; lt = gt7; }

// ---------------------------------------------------------------------------
// squared norms of x rows
// ---------------------------------------------------------------------------
__global__ __launch_bounds__(256) void sq_kernel(const float* __restrict__ x,
                                                 float* __restrict__ sqx) {
  int gid = blockIdx.x * 256 + threadIdx.x;  // 0..32767
  float a = x[gid * 3 + 0];
  float b = x[gid * 3 + 1];
  float c = x[gid * 3 + 2];
  sqx[gid] = a * a + b * b + c * c;
}

// ---------------------------------------------------------------------------
// stage-1 knn on xyz; one wave per row; no per-lane arrays anywhere
// ---------------------------------------------------------------------------
__global__ __launch_bounds__(256) void knn1_kernel(const float* __restrict__ x,
                                                   const float* __restrict__ sqx,
                                                   int* __restrict__ idx1) {
  int wave = threadIdx.x >> 6, lane = threadIdx.x & 63;
  int row = blockIdx.x * 4 + wave;      // global row
  int b = row >> 12;                    // /4096
  int i = row & (NP - 1);
  const float* xb = x + (size_t)b * NP * 3;
  const float* sqb = sqx + b * NP;
  float xi0 = xb[i * 3 + 0], xi1 = xb[i * 3 + 1], xi2 = xb[i * 3 + 2];

  float gv0, gv1, gv2, gv3, gv4, gv5, gv6, gv7;
  int   gt0, gt1, gt2, gt3, gt4, gt5, gt6, gt7;
  unsigned rm0 = 0u, rm1 = 0u;
  knn1_group<0>(xb, sqb, lane, xi0, xi1, xi2, 0u, gv0, gt0);
  knn1_group<1>(xb, sqb, lane, xi0, xi1, xi2, 0u, gv1, gt1);
  knn1_group<2>(xb, sqb, lane, xi0, xi1, xi2, 0u, gv2, gt2);
  knn1_group<3>(xb, sqb, lane, xi0, xi1, xi2, 0u, gv3, gt3);
  knn1_group<4>(xb, sqb, lane, xi0, xi1, xi2, 0u, gv4, gt4);
  knn1_group<5>(xb, sqb, lane, xi0, xi1, xi2, 0u, gv5, gt5);
  knn1_group<6>(xb, sqb, lane, xi0, xi1, xi2, 0u, gv6, gt6);
  knn1_group<7>(xb, sqb, lane, xi0, xi1, xi2, 0u, gv7, gt7);
  float lv; int lt;
  LANE_SCAN();

  int myidx = 0;
  #pragma unroll 1
  for (int r = 0; r < KNN; ++r) {
    float mv = lv;
    int mj = (lane << 6) | lt;
    #pragma unroll
    for (int off = 32; off; off >>= 1) {
      float om = __shfl_xor(mv, off, 64);
      int   oj = __shfl_xor(mj, off, 64);
      if (om > mv || (om == mv && oj < mj)) { mv = om; mj = oj; }
    }
    if (lane == r) myidx = mj;
    int mju = __builtin_amdgcn_readfirstlane(mj);
    int wl = mju >> 6, tu = mju & 63;
    if (lane == wl) {
      switch (tu >> 3) {
        case 0: rm0 |= 1u << (tu & 7);        knn1_group<0>(xb, sqb, lane, xi0, xi1, xi2, rm0 & 0xffu,         gv0, gt0); break;
        case 1: rm0 |= 1u << (8 + (tu & 7));  knn1_group<1>(xb, sqb, lane, xi0, xi1, xi2, (rm0 >> 8) & 0xffu,  gv1, gt1); break;
        case 2: rm0 |= 1u << (16 + (tu & 7)); knn1_group<2>(xb, sqb, lane, xi0, xi1, xi2, (rm0 >> 16) & 0xffu, gv2, gt2); break;
        case 3: rm0 |= 1u << (24 + (tu & 7)); knn1_group<3>(xb, sqb, lane, xi0, xi1, xi2, (rm0 >> 24) & 0xffu, gv3, gt3); break;
        case 4: rm1 |= 1u << (tu & 7);        knn1_group<4>(xb, sqb, lane, xi0, xi1, xi2, rm1 & 0xffu,         gv4, gt4); break;
        case 5: rm1 |= 1u << (8 + (tu & 7));  knn1_group<5>(xb, sqb, lane, xi0, xi1, xi2, (rm1 >> 8) & 0xffu,  gv5, gt5); break;
        case 6: rm1 |= 1u << (16 + (tu & 7)); knn1_group<6>(xb, sqb, lane, xi0, xi1, xi2, (rm1 >> 16) & 0xffu, gv6, gt6); break;
        case 7: rm1 |= 1u << (24 + (tu & 7)); knn1_group<7>(xb, sqb, lane, xi0, xi1, xi2, (rm1 >> 24) & 0xffu, gv7, gt7); break;
      }
      LANE_SCAN();
    }
  }
  if (lane < KNN) idx1[(size_t)row * KNN + lane] = myidx;
}

// ---------------------------------------------------------------------------
// F1[j] = mlp1(x[0,j])  (3->64 relu ->64 relu ->64), one wave per row
// ---------------------------------------------------------------------------
__global__ __launch_bounds__(256) void mlp1_kernel(const float* __restrict__ x,
                                                   const float* __restrict__ w1, const float* __restrict__ b1,
                                                   const float* __restrict__ w2, const float* __restrict__ b2,
                                                   const float* __restrict__ w3, const float* __restrict__ b3,
                                                   float* __restrict__ F1) {
  int wave = threadIdx.x >> 6, lane = threadIdx.x & 63;
  int j = blockIdx.x * 4 + wave;        // 0..4095 (batch 0 rows)
  float x0 = x[j * 3 + 0], x1 = x[j * 3 + 1], x2 = x[j * 3 + 2];
  float h1 = fmaf(x2, w1[128 + lane], fmaf(x1, w1[64 + lane], fmaf(x0, w1[lane], b1[lane])));
  h1 = fmaxf(h1, 0.f);
  float acc = b2[lane];
  #pragma unroll
  for (int c = 0; c < 64; ++c) acc = fmaf(__shfl(h1, c, 64), w2[c * 64 + lane], acc);
  float h2 = fmaxf(acc, 0.f);
  acc = b3[lane];
  #pragma unroll
  for (int c = 0; c < 64; ++c) acc = fmaf(__shfl(h2, c, 64), w3[c * 64 + lane], acc);
  F1[j * 64 + lane] = acc;
}

// ---------------------------------------------------------------------------
// h[row] = max_k F1[idx1[row,k]] ; sqh[row] = ||h[row]||^2
// ---------------------------------------------------------------------------
__global__ __launch_bounds__(256) void pool1_kernel(const float* __restrict__ F1,
                                                    const int* __restrict__ idx1,
                                                    float* __restrict__ h,
                                                    float* __restrict__ sqh) {
  int wave = threadIdx.x >> 6, lane = threadIdx.x & 63;
  int row = blockIdx.x * 4 + wave;
  float m = NEGF;
  #pragma unroll
  for (int k = 0; k < KNN; ++k) {
    int jj = idx1[(size_t)row * KNN + k];
    m = fmaxf(m, F1[jj * 64 + lane]);
  }
  h[(size_t)row * 64 + lane] = m;
  float s = m * m;
  #pragma unroll
  for (int off = 32; off; off >>= 1) s += __shfl_xor(s, off, 64);
  if (lane == 0) sqh[row] = s;
}

// ---------------------------------------------------------------------------
// pd[i][j] = 2*h_i.h_j - sq_i - sq_j for one batch (4096x4096x64 f32 GEMM)
// ---------------------------------------------------------------------------
__device__ __forceinline__ int swz(int g, int r) { return g ^ ((r & 15) ^ ((r >> 4) & 3)); }

__global__ __launch_bounds__(256) void pd_gemm_kernel(const float* __restrict__ h,
                                                      const float* __restrict__ sqh,
                                                      float* __restrict__ pd, int b) {
  __shared__ float As[64 * 64];
  __shared__ float Bs[64 * 64];
  const int it = blockIdx.x >> 6;
  const int jt = blockIdx.x & 63;
  const int i0 = it * 64, j0 = jt * 64;
  const float* hb = h + (size_t)b * NP * 64;
  const int tid = threadIdx.x;
  #pragma unroll
  for (int s = 0; s < 4; ++s) {
    int f4 = tid + s * 256;
    int r = f4 >> 4, g = f4 & 15;
    int gs = swz(g, r);
    float4 va = *reinterpret_cast<const float4*>(&hb[(size_t)(i0 + r) * 64 + g * 4]);
    *reinterpret_cast<float4*>(&As[r * 64 + gs * 4]) = va;
    float4 vb = *reinterpret_cast<const float4*>(&hb[(size_t)(j0 + r) * 64 + g * 4]);
    *reinterpret_cast<float4*>(&Bs[r * 64 + gs * 4]) = vb;
  }
  __syncthreads();
  const int tx = tid & 15, ty = tid >> 4;
  float acc[4][4] = {};
  #pragma unroll
  for (int c = 0; c < 64; c += 4) {
    int g = c >> 2;
    float4 a[4], bb[4];
    #pragma unroll
    for (int q = 0; q < 4; ++q) {
      int r = ty * 4 + q;
      a[q] = *reinterpret_cast<const float4*>(&As[r * 64 + (swz(g, r) << 2)]);
    }
    #pragma unroll
    for (int p = 0; p < 4; ++p) {
      int r = tx * 4 + p;
      bb[p] = *reinterpret_cast<const float4*>(&Bs[r * 64 + (swz(g, r) << 2)]);
    }
    #pragma unroll
    for (int q = 0; q < 4; ++q) {
      #pragma unroll
      for (int p = 0; p < 4; ++p) {
        acc[q][p] = fmaf(a[q].x, bb[p].x, acc[q][p]);
        acc[q][p] = fmaf(a[q].y, bb[p].y, acc[q][p]);
        acc[q][p] = fmaf(a[q].z, bb[p].z, acc[q][p]);
        acc[q][p] = fmaf(a[q].w, bb[p].w, acc[q][p]);
      }
    }
  }
  const float* sq = sqh + b * NP;
  float sj0 = sq[j0 + tx * 4 + 0];
  float sj1 = sq[j0 + tx * 4 + 1];
  float sj2 = sq[j0 + tx * 4 + 2];
  float sj3 = sq[j0 + tx * 4 + 3];
  #pragma unroll
  for (int q = 0; q < 4; ++q) {
    int i = i0 + ty * 4 + q;
    float sqi = sq[i];
    float4 o;
    o.x = 2.f * acc[q][0] - sqi - sj0;
    o.y = 2.f * acc[q][1] - sqi - sj1;
    o.z = 2.f * acc[q][2] - sqi - sj2;
    o.w = 2.f * acc[q][3] - sqi - sj3;
    *reinterpret_cast<float4*>(&pd[(size_t)i * NP + j0 + tx * 4]) = o;
  }
}

// ---------------------------------------------------------------------------
// top-20 from materialized pd rows (one batch); spill-free cached top-k
// ---------------------------------------------------------------------------
__global__ __launch_bounds__(256) void knn_select_kernel(const float* __restrict__ pd,
                                                         int* __restrict__ idx2, int b) {
  int wave = threadIdx.x >> 6, lane = threadIdx.x & 63;
  int row = blockIdx.x * 4 + wave;      // local row in batch
  const float* prow = pd + (size_t)row * NP + (lane << 6);

  float gv0, gv1, gv2, gv3, gv4, gv5, gv6, gv7;
  int   gt0, gt1, gt2, gt3, gt4, gt5, gt6, gt7;
  unsigned rm0 = 0u, rm1 = 0u;
  sel_group<0>(prow, 0u, gv0, gt0);
  sel_group<1>(prow, 0u, gv1, gt1);
  sel_group<2>(prow, 0u, gv2, gt2);
  sel_group<3>(prow, 0u, gv3, gt3);
  sel_group<4>(prow, 0u, gv4, gt4);
  sel_group<5>(prow, 0u, gv5, gt5);
  sel_group<6>(prow, 0u, gv6, gt6);
  sel_group<7>(prow, 0u, gv7, gt7);
  float lv; int lt;
  LANE_SCAN();

  int myidx = 0;
  #pragma unroll 1
  for (int r = 0; r < KNN; ++r) {
    float mv = lv;
    int mj = (lane << 6) | lt;
    #pragma unroll
    for (int off = 32; off; off >>= 1) {
      float om = __shfl_xor(mv, off, 64);
      int   oj = __shfl_xor(mj, off, 64);
      if (om > mv || (om == mv && oj < mj)) { mv = om; mj = oj; }
    }
    if (lane == r) myidx = mj;
    int mju = __builtin_amdgcn_readfirstlane(mj);
    int wl = mju >> 6, tu = mju & 63;
    if (lane == wl) {
      switch (tu >> 3) {
        case 0: rm0 |= 1u << (tu & 7);        sel_group<0>(prow, rm0 & 0xffu,         gv0, gt0); break;
        case 1: rm0 |= 1u << (8 + (tu & 7));  sel_group<1>(prow, (rm0 >> 8) & 0xffu,  gv1, gt1); break;
        case 2: rm0 |= 1u << (16 + (tu & 7)); sel_group<2>(prow, (rm0 >> 16) & 0xffu, gv2, gt2); break;
        case 3: rm0 |= 1u << (24 + (tu & 7)); sel_group<3>(prow, (rm0 >> 24) & 0xffu, gv3, gt3); break;
        case 4: rm1 |= 1u << (tu & 7);        sel_group<4>(prow, rm1 & 0xffu,         gv4, gt4); break;
        case 5: rm1 |= 1u << (8 + (tu & 7));  sel_group<5>(prow, (rm1 >> 8) & 0xffu,  gv5, gt5); break;
        case 6: rm1 |= 1u << (16 + (tu & 7)); sel_group<6>(prow, (rm1 >> 16) & 0xffu, gv6, gt6); break;
        case 7: rm1 |= 1u << (24 + (tu & 7)); sel_group<7>(prow, (rm1 >> 24) & 0xffu, gv7, gt7); break;
      }
      LANE_SCAN();
    }
  }
  if (lane < KNN) idx2[(size_t)(b * NP + row) * KNN + lane] = myidx;
}

// ---------------------------------------------------------------------------
// fallback fused knn2 (no pd buffer): R0-style full-rescan topk (path is
// normally unused; kept for small-ws safety)
// ---------------------------------------------------------------------------
__device__ __forceinline__ void clear_slot_fb(float (&val)[64], int tw, int lw, int lane) {
  switch (tw) {
#define CS(T) case T: if (lane == lw) val[T] = NEGF; break;
    CS(0) CS(1) CS(2) CS(3) CS(4) CS(5) CS(6) CS(7)
    CS(8) CS(9) CS(10) CS(11) CS(12) CS(13) CS(14) CS(15)
    CS(16) CS(17) CS(18) CS(19) CS(20) CS(21) CS(22) CS(23)
    CS(24) CS(25) CS(26) CS(27) CS(28) CS(29) CS(30) CS(31)
    CS(32) CS(33) CS(34) CS(35) CS(36) CS(37) CS(38) CS(39)
    CS(40) CS(41) CS(42) CS(43) CS(44) CS(45) CS(46) CS(47)
    CS(48) CS(49) CS(50) CS(51) CS(52) CS(53) CS(54) CS(55)
    CS(56) CS(57) CS(58) CS(59) CS(60) CS(61) CS(62) CS(63)
#undef CS
  }
}

__device__ __forceinline__ void wave_topk_fb(float (&val)[64], int lane, int rowbase,
                                             int* __restrict__ idx_out) {
  int myidx = 0;
  #pragma unroll 1
  for (int r = 0; r < KNN; ++r) {
    float m[4]; int mt[4];
    #pragma unroll
    for (int q = 0; q < 4; ++q) { m[q] = val[q]; mt[q] = q; }
    #pragma unroll
    for (int t = 4; t < 64; t += 4) {
      #pragma unroll
      for (int q = 0; q < 4; ++q) {
        if (val[t + q] > m[q]) { m[q] = val[t + q]; mt[q] = t + q; }
      }
    }
    if (m[1] > m[0] || (m[1] == m[0] && mt[1] < mt[0])) { m[0] = m[1]; mt[0] = mt[1]; }
    if (m[3] > m[2] || (m[3] == m[2] && mt[3] < mt[2])) { m[2] = m[3]; mt[2] = mt[3]; }
    if (m[2] > m[0] || (m[2] == m[0] && mt[2] < mt[0])) { m[0] = m[2]; mt[0] = mt[2]; }
    float mv = m[0];
    int mj = mt[0] * 64 + lane;
    #pragma unroll
    for (int off = 32; off; off >>= 1) {
      float om = __shfl_xor(mv, off, 64);
      int   oj = __shfl_xor(mj, off, 64);
      if (om > mv || (om == mv && oj < mj)) { mv = om; mj = oj; }
    }
    clear_slot_fb(val, mj >> 6, mj & 63, lane);
    if (lane == r) myidx = mj;
  }
  if (lane < KNN) idx_out[(size_t)rowbase * KNN + lane] = myidx;
}

__global__ __launch_bounds__(512) void knn2_fused_kernel(const float* __restrict__ h,
                                                         const float* __restrict__ sqh,
                                                         int* __restrict__ idx2) {
  __shared__ float tile[64 * 64];
  const int wave = threadIdx.x >> 6, lane = threadIdx.x & 63;
  const int row = blockIdx.x * 8 + wave;
  const int b = row >> 12;
  const int jb = b * NP;
  float hi[64];
  #pragma unroll
  for (int q2 = 0; q2 < 16; ++q2) {
    float4 v = *reinterpret_cast<const float4*>(&h[(size_t)row * 64 + q2 * 4]);
    hi[q2 * 4 + 0] = v.x; hi[q2 * 4 + 1] = v.y; hi[q2 * 4 + 2] = v.z; hi[q2 * 4 + 3] = v.w;
  }
  float sqi = sqh[row];
  float val[64];
  #pragma unroll
  for (int tt = 0; tt < 64; ++tt) {
    __syncthreads();
    #pragma unroll
    for (int s = 0; s < 2; ++s) {
      int f4 = threadIdx.x + s * 512;
      int jj = f4 >> 4, g = f4 & 15;
      float4 v = *reinterpret_cast<const float4*>(&h[(size_t)(jb + tt * 64 + jj) * 64 + g * 4]);
      int gs = g ^ (jj & 15);
      *reinterpret_cast<float4*>(&tile[jj * 64 + gs * 4]) = v;
    }
    __syncthreads();
    float acc = 0.f;
    #pragma unroll
    for (int g = 0; g < 16; ++g) {
      int gs = g ^ (lane & 15);
      float4 v = *reinterpret_cast<const float4*>(&tile[lane * 64 + gs * 4]);
      acc = fmaf(hi[4 * g + 0], v.x, acc);
      acc = fmaf(hi[4 * g + 1], v.y, acc);
      acc = fmaf(hi[4 * g + 2], v.z, acc);
      acc = fmaf(hi[4 * g + 3], v.w, acc);
    }
    val[tt] = 2.f * acc - sqi - sqh[jb + tt * 64 + lane];
  }
  wave_topk_fb(val, lane, row, idx2);
}

// ---------------------------------------------------------------------------
// G4[j] = h[0,j] @ w4 + b4  (64 -> 128)
// ---------------------------------------------------------------------------
__global__ __launch_bounds__(128) void g4_kernel(const float* __restrict__ h,
                                                 const float* __restrict__ w4,
                                                 const float* __restrict__ b4,
                                                 float* __restrict__ G4) {
  __shared__ float hj[64];
  int j = blockIdx.x;
  int o = threadIdx.x;
  if (o < 64) hj[o] = h[(size_t)j * 64 + o];
  __syncthreads();
  float acc = b4[o];
  #pragma unroll
  for (int c = 0; c < 64; ++c) acc = fmaf(hj[c], w4[c * 128 + o], acc);
  G4[(size_t)j * 128 + o] = acc;
}

// ---------------------------------------------------------------------------
// h2[row] = max_k G4[idx2[row,k]]
// ---------------------------------------------------------------------------
__global__ __launch_bounds__(256) void pool2_kernel(const float* __restrict__ G4,
                                                    const int* __restrict__ idx2,
                                                    float* __restrict__ h2) {
  int gid = blockIdx.x * 256 + threadIdx.x;
  int row = gid >> 7, o = gid & 127;
  float m = NEGF;
  #pragma unroll
  for (int k = 0; k < KNN; ++k) {
    int jj = idx2[(size_t)row * KNN + k];
    m = fmaxf(m, G4[(size_t)jj * 128 + o]);
  }
  h2[(size_t)gid] = m;
}

// ---------------------------------------------------------------------------
// out = h2 @ w5 + b5  (32768 x 1024 x 128), 64x64 tile, 4x4/thread
// ---------------------------------------------------------------------------
__global__ __launch_bounds__(256) void final_gemm_kernel(const float* __restrict__ h2,
                                                         const float* __restrict__ w5,
                                                         const float* __restrict__ b5,
                                                         float* __restrict__ out) {
  __shared__ float As[64 * 128];
  __shared__ float Bs[128 * 64];
  const int mt = blockIdx.x >> 4;
  const int nt = blockIdx.x & 15;
  const int row0 = mt * 64, col0 = nt * 64;
  const int tid = threadIdx.x;
  #pragma unroll
  for (int s = 0; s < 8; ++s) {
    int f4 = tid + s * 256;
    int i = f4 >> 5, kf = f4 & 31;
    float4 v = *reinterpret_cast<const float4*>(&h2[(size_t)(row0 + i) * 128 + kf * 4]);
    *reinterpret_cast<float4*>(&As[i * 128 + kf * 4]) = v;
  }
  #pragma unroll
  for (int s = 0; s < 8; ++s) {
    int f4 = tid + s * 256;
    int k = f4 >> 4, g = f4 & 15;
    float4 v = *reinterpret_cast<const float4*>(&w5[(size_t)k * 1024 + col0 + g * 4]);
    *reinterpret_cast<float4*>(&Bs[k * 64 + g * 4]) = v;
  }
  __syncthreads();
  const int tx = tid & 15, ty = tid >> 4;
  float acc[4][4] = {};
  #pragma unroll
  for (int k = 0; k < 128; k += 4) {
    float4 a[4], bb[4];
    #pragma unroll
    for (int q = 0; q < 4; ++q)
      a[q] = *reinterpret_cast<const float4*>(&As[(ty * 4 + q) * 128 + k]);
    #pragma unroll
    for (int kk = 0; kk < 4; ++kk)
      bb[kk] = *reinterpret_cast<const float4*>(&Bs[(k + kk) * 64 + tx * 4]);
    #pragma unroll
    for (int q = 0; q < 4; ++q) {
      acc[q][0] = fmaf(a[q].w, bb[3].x, fmaf(a[q].z, bb[2].x, fmaf(a[q].y, bb[1].x, fmaf(a[q].x, bb[0].x, acc[q][0]))));
      acc[q][1] = fmaf(a[q].w, bb[3].y, fmaf(a[q].z, bb[2].y, fmaf(a[q].y, bb[1].y, fmaf(a[q].x, bb[0].y, acc[q][1]))));
      acc[q][2] = fmaf(a[q].w, bb[3].z, fmaf(a[q].z, bb[2].z, fmaf(a[q].y, bb[1].z, fmaf(a[q].x, bb[0].z, acc[q][2]))));
      acc[q][3] = fmaf(a[q].w, bb[3].w, fmaf(a[q].z, bb[2].w, fmaf(a[q].y, bb[1].w, fmaf(a[q].x, bb[0].w, acc[q][3]))));
    }
  }
  float b0 = b5[col0 + tx * 4 + 0];
  float b1 = b5[col0 + tx * 4 + 1];
  float b2 = b5[col0 + tx * 4 + 2];
  float b3 = b5[col0 + tx * 4 + 3];
  #pragma unroll
  for (int q = 0; q < 4; ++q) {
    float4 o;
    o.x = acc[q][0] + b0;
    o.y = acc[q][1] + b1;
    o.z = acc[q][2] + b2;
    o.w = acc[q][3] + b3;
    *reinterpret_cast<float4*>(&out[(size_t)(row0 + ty * 4 + q) * 1024 + col0 + tx * 4]) = o;
  }
}

// ---------------------------------------------------------------------------
extern "C" void kernel_launch(void* const* d_in, const int* in_sizes, int n_in,
                              void* d_out, int out_size, void* d_ws, size_t ws_size,
                              hipStream_t stream) {
  const float* x  = (const float*)d_in[0];
  const float* w1 = (const float*)d_in[1];
  const float* b1 = (const float*)d_in[2];
  const float* w2 = (const float*)d_in[3];
  const float* b2 = (const float*)d_in[4];
  const float* w3 = (const float*)d_in[5];
  const float* b3 = (const float*)d_in[6];
  const float* w4 = (const float*)d_in[7];
  const float* b4 = (const float*)d_in[8];
  const float* w5 = (const float*)d_in[9];
  const float* b5 = (const float*)d_in[10];
  float* out = (float*)d_out;
  char* ws = (char*)d_ws;

  // layout (bytes)
  float* h    = (float*)(ws + 0);                       //  8,388,608
  float* sqh  = (float*)(ws + 8388608);                 //    131,072
  int*   idx2 = (int*)  (ws + 8519680);                 //  2,621,440
  char*  X    = ws + 11141120;                          // overlay region
  float* sqx  = (float*)(X + 0);                        //    131,072 (dead after knn1)
  int*   idx1 = (int*)  (X + 131072);                   //  2,621,440 (dead after pool1)
  float* F1   = (float*)(X + 2752512);                  //  1,048,576 (dead after pool1)
  float* pd   = (float*)(X + 0);                        // 67,108,864 (live only during knn2 fast path)
  float* G4   = (float*)(X + 0);                        //  2,097,152 (after knn2)
  float* h2   = (float*)(X + 2097152);                  // 16,777,216 (after knn2)

  const size_t NEED_FAST = 11141120 + 67108864;

  sq_kernel<<<128, 256, 0, stream>>>(x, sqx);
  knn1_kernel<<<8192, 256, 0, stream>>>(x, sqx, idx1);
  mlp1_kernel<<<1024, 256, 0, stream>>>(x, w1, b1, w2, b2, w3, b3, F1);
  pool1_kernel<<<8192, 256, 0, stream>>>(F1, idx1, h, sqh);

  if (ws_size >= NEED_FAST) {
    for (int b = 0; b < NBATCH; ++b) {
      pd_gemm_kernel<<<4096, 256, 0, stream>>>(h, sqh, pd, b);
      knn_select_kernel<<<1024, 256, 0, stream>>>(pd, idx2, b);
    }
  } else {
    knn2_fused_kernel<<<4096, 512, 0, stream>>>(h, sqh, idx2);
  }

  g4_kernel<<<4096, 128, 0, stream>>>(h, w4, b4, G4);
  pool2_kernel<<<16384, 256, 0, stream>>>(G4, idx2, h2);
  final_gemm_kernel<<<8192, 256, 0, stream>>>(h2, w5, b5, out);
}

// Round 5
// 1022.572 us; speedup vs baseline: 1.4583x; 1.1559x over previous
//
#include <hip/hip_runtime.h>
#include <stddef.h>

#define NBATCH 8
#define NP 4096
#define KNN 20
#define NEGF (-3.402823466e38f)

// ===========================================================================
// DPP wave-max (canonical 6-level VALU reduction, result valid in lane 63,
// broadcast via readlane). ~2-4cy/level vs ~120cy/level for ds_swizzle.
// ===========================================================================
__device__ __forceinline__ float wave_max_f32(float v) {
  int b = __float_as_int(v), t;
  t = __builtin_amdgcn_update_dpp(b, b, 0xB1, 0xf, 0xf, false);   // quad_perm [1,0,3,2] (xor1)
  b = __float_as_int(fmaxf(__int_as_float(b), __int_as_float(t)));
  t = __builtin_amdgcn_update_dpp(b, b, 0x4E, 0xf, 0xf, false);   // quad_perm [2,3,0,1] (xor2)
  b = __float_as_int(fmaxf(__int_as_float(b), __int_as_float(t)));
  t = __builtin_amdgcn_update_dpp(b, b, 0x124, 0xf, 0xf, false);  // row_ror:4
  b = __float_as_int(fmaxf(__int_as_float(b), __int_as_float(t)));
  t = __builtin_amdgcn_update_dpp(b, b, 0x128, 0xf, 0xf, false);  // row_ror:8 -> row16 max
  b = __float_as_int(fmaxf(__int_as_float(b), __int_as_float(t)));
  t = __builtin_amdgcn_update_dpp(b, b, 0x142, 0xa, 0xf, false);  // bcast15 -> rows 1,3
  b = __float_as_int(fmaxf(__int_as_float(b), __int_as_float(t)));
  t = __builtin_amdgcn_update_dpp(b, b, 0x143, 0xc, 0xf, false);  // bcast31 -> rows 2,3
  b = __float_as_int(fmaxf(__int_as_float(b), __int_as_float(t)));
  return __int_as_float(__builtin_amdgcn_readlane(b, 63));
}

// ===========================================================================
// Spill-free top-20 state: named scalars only (group maxes gv0..7/gt0..7,
// removal bitmask rm0/rm1, running lane max lv/lt). Owner lane recomputes its
// 8-candidate group on removal. j = lane*64 + t (lane-major).
// ===========================================================================

// ---- group-max for knn1: recompute 8 distances from x (scores = 2*dot - sqj;
//      the -sqi term is constant per row and dropped: selection-invariant) ----
template<int G>
__device__ __forceinline__ void knn1_group(const float* __restrict__ xb,
                                           const float* __restrict__ sqb,
                                           int lane, float xi0, float xi1, float xi2,
                                           unsigned mask8, float& gmv, int& gmt) {
  const float* xg = xb + 3 * ((lane << 6) | (G * 8));
  const float* sg = sqb + ((lane << 6) | (G * 8));
  float4 v0 = *(const float4*)(xg + 0);
  float4 v1 = *(const float4*)(xg + 4);
  float4 v2 = *(const float4*)(xg + 8);
  float4 v3 = *(const float4*)(xg + 12);
  float4 v4 = *(const float4*)(xg + 16);
  float4 v5 = *(const float4*)(xg + 20);
  float4 s0 = *(const float4*)(sg + 0);
  float4 s1 = *(const float4*)(sg + 4);
  float d0 = fmaf(xi2, v0.z, fmaf(xi1, v0.y, xi0 * v0.x)); d0 = fmaf(d0, 2.f, -s0.x);
  float d1 = fmaf(xi2, v1.y, fmaf(xi1, v1.x, xi0 * v0.w)); d1 = fmaf(d1, 2.f, -s0.y);
  float d2 = fmaf(xi2, v2.x, fmaf(xi1, v1.w, xi0 * v1.z)); d2 = fmaf(d2, 2.f, -s0.z);
  float d3 = fmaf(xi2, v2.w, fmaf(xi1, v2.z, xi0 * v2.y)); d3 = fmaf(d3, 2.f, -s0.w);
  float d4 = fmaf(xi2, v3.z, fmaf(xi1, v3.y, xi0 * v3.x)); d4 = fmaf(d4, 2.f, -s1.x);
  float d5 = fmaf(xi2, v4.y, fmaf(xi1, v4.x, xi0 * v3.w)); d5 = fmaf(d5, 2.f, -s1.y);
  float d6 = fmaf(xi2, v5.x, fmaf(xi1, v4.w, xi0 * v4.z)); d6 = fmaf(d6, 2.f, -s1.z);
  float d7 = fmaf(xi2, v5.w, fmaf(xi1, v5.z, xi0 * v5.y)); d7 = fmaf(d7, 2.f, -s1.w);
  if (mask8 & 1u)   d0 = NEGF;
  if (mask8 & 2u)   d1 = NEGF;
  if (mask8 & 4u)   d2 = NEGF;
  if (mask8 & 8u)   d3 = NEGF;
  if (mask8 & 16u)  d4 = NEGF;
  if (mask8 & 32u)  d5 = NEGF;
  if (mask8 & 64u)  d6 = NEGF;
  if (mask8 & 128u) d7 = NEGF;
  float mv = d0; int mt = 0;
  if (d1 > mv) { mv = d1; mt = 1; }
  if (d2 > mv) { mv = d2; mt = 2; }
  if (d3 > mv) { mv = d3; mt = 3; }
  if (d4 > mv) { mv = d4; mt = 4; }
  if (d5 > mv) { mv = d5; mt = 5; }
  if (d6 > mv) { mv = d6; mt = 6; }
  if (d7 > mv) { mv = d7; mt = 7; }
  gmv = mv; gmt = G * 8 + mt;
}

// ---- group-max for knn_select: reload 8 pd values (L1/L2-hot) ----
template<int G>
__device__ __forceinline__ void sel_group(const float* __restrict__ prow,
                                          unsigned mask8, float& gmv, int& gmt) {
  float4 a = *(const float4*)(prow + G * 8);
  float4 b = *(const float4*)(prow + G * 8 + 4);
  float d0 = a.x, d1 = a.y, d2 = a.z, d3 = a.w;
  float d4 = b.x, d5 = b.y, d6 = b.z, d7 = b.w;
  if (mask8 & 1u)   d0 = NEGF;
  if (mask8 & 2u)   d1 = NEGF;
  if (mask8 & 4u)   d2 = NEGF;
  if (mask8 & 8u)   d3 = NEGF;
  if (mask8 & 16u)  d4 = NEGF;
  if (mask8 & 32u)  d5 = NEGF;
  if (mask8 & 64u)  d6 = NEGF;
  if (mask8 & 128u) d7 = NEGF;
  float mv = d0; int mt = 0;
  if (d1 > mv) { mv = d1; mt = 1; }
  if (d2 > mv) { mv = d2; mt = 2; }
  if (d3 > mv) { mv = d3; mt = 3; }
  if (d4 > mv) { mv = d4; mt = 4; }
  if (d5 > mv) { mv = d5; mt = 5; }
  if (d6 > mv) { mv = d6; mt = 6; }
  if (d7 > mv) { mv = d7; mt = 7; }
  gmv = mv; gmt = G * 8 + mt;
}

#define LANE_SCAN()                                            \
  lv = gv0; lt = gt0;                                          \
  if (gv1 > lv) { lv = gv1; lt = gt1; }                        \
  if (gv2 > lv) { lv = gv2; lt = gt2; }                        \
  if (gv3 > lv) { lv = gv3; lt = gt3; }                        \
  if (gv4 > lv) { lv = gv4; lt = gt4; }                        \
  if (gv5 > lv) { lv = gv5; lt = gt5; }                        \
  if (gv6 > lv) { lv = gv6; lt = gt6; }                        \
  if (gv7 > lv) { lv = gv7; lt = gt7; }

// ---------------------------------------------------------------------------
// squared norms of x rows
// ---------------------------------------------------------------------------
__global__ __launch_bounds__(256) void sq_kernel(const float* __restrict__ x,
                                                 float* __restrict__ sqx) {
  int gid = blockIdx.x * 256 + threadIdx.x;  // 0..32767
  float a = x[gid * 3 + 0];
  float b = x[gid * 3 + 1];
  float c = x[gid * 3 + 2];
  sqx[gid] = a * a + b * b + c * c;
}

// ---------------------------------------------------------------------------
// stage-1 knn on xyz; one wave per row; DPP-max + ballot extraction
// ---------------------------------------------------------------------------
__global__ __launch_bounds__(256) void knn1_kernel(const float* __restrict__ x,
                                                   const float* __restrict__ sqx,
                                                   int* __restrict__ idx1) {
  int wave = threadIdx.x >> 6, lane = threadIdx.x & 63;
  int row = blockIdx.x * 4 + wave;      // global row
  int b = row >> 12;                    // /4096
  int i = row & (NP - 1);
  const float* xb = x + (size_t)b * NP * 3;
  const float* sqb = sqx + b * NP;
  float xi0 = xb[i * 3 + 0], xi1 = xb[i * 3 + 1], xi2 = xb[i * 3 + 2];

  float gv0, gv1, gv2, gv3, gv4, gv5, gv6, gv7;
  int   gt0, gt1, gt2, gt3, gt4, gt5, gt6, gt7;
  unsigned rm0 = 0u, rm1 = 0u;
  knn1_group<0>(xb, sqb, lane, xi0, xi1, xi2, 0u, gv0, gt0);
  knn1_group<1>(xb, sqb, lane, xi0, xi1, xi2, 0u, gv1, gt1);
  knn1_group<2>(xb, sqb, lane, xi0, xi1, xi2, 0u, gv2, gt2);
  knn1_group<3>(xb, sqb, lane, xi0, xi1, xi2, 0u, gv3, gt3);
  knn1_group<4>(xb, sqb, lane, xi0, xi1, xi2, 0u, gv4, gt4);
  knn1_group<5>(xb, sqb, lane, xi0, xi1, xi2, 0u, gv5, gt5);
  knn1_group<6>(xb, sqb, lane, xi0, xi1, xi2, 0u, gv6, gt6);
  knn1_group<7>(xb, sqb, lane, xi0, xi1, xi2, 0u, gv7, gt7);
  float lv; int lt;
  LANE_SCAN();

  int myidx = 0;
  #pragma unroll 1
  for (int r = 0; r < KNN; ++r) {
    float m = wave_max_f32(lv);
    unsigned long long bal = __ballot(lv == m);
    int wl = (int)__builtin_ctzll(bal);          // smallest lane among ties = smallest j
    int tsel = __builtin_amdgcn_readlane(lt, wl);
    if (lane == r) myidx = (wl << 6) | tsel;
    if (lane == wl) {
      switch (tsel >> 3) {
        case 0: rm0 |= 1u << (tsel & 7);        knn1_group<0>(xb, sqb, lane, xi0, xi1, xi2, rm0 & 0xffu,         gv0, gt0); break;
        case 1: rm0 |= 1u << (8 + (tsel & 7));  knn1_group<1>(xb, sqb, lane, xi0, xi1, xi2, (rm0 >> 8) & 0xffu,  gv1, gt1); break;
        case 2: rm0 |= 1u << (16 + (tsel & 7)); knn1_group<2>(xb, sqb, lane, xi0, xi1, xi2, (rm0 >> 16) & 0xffu, gv2, gt2); break;
        case 3: rm0 |= 1u << (24 + (tsel & 7)); knn1_group<3>(xb, sqb, lane, xi0, xi1, xi2, (rm0 >> 24) & 0xffu, gv3, gt3); break;
        case 4: rm1 |= 1u << (tsel & 7);        knn1_group<4>(xb, sqb, lane, xi0, xi1, xi2, rm1 & 0xffu,         gv4, gt4); break;
        case 5: rm1 |= 1u << (8 + (tsel & 7));  knn1_group<5>(xb, sqb, lane, xi0, xi1, xi2, (rm1 >> 8) & 0xffu,  gv5, gt5); break;
        case 6: rm1 |= 1u << (16 + (tsel & 7)); knn1_group<6>(xb, sqb, lane, xi0, xi1, xi2, (rm1 >> 16) & 0xffu, gv6, gt6); break;
        case 7: rm1 |= 1u << (24 + (tsel & 7)); knn1_group<7>(xb, sqb, lane, xi0, xi1, xi2, (rm1 >> 24) & 0xffu, gv7, gt7); break;
      }
      LANE_SCAN();
    }
  }
  if (lane < KNN) idx1[(size_t)row * KNN + lane] = myidx;
}

// ---------------------------------------------------------------------------
// shared select body: top-20 of one materialized pd row
// ---------------------------------------------------------------------------
__device__ __forceinline__ void select_row(const float* __restrict__ prow,
                                           int lane, int* __restrict__ out) {
  float gv0, gv1, gv2, gv3, gv4, gv5, gv6, gv7;
  int   gt0, gt1, gt2, gt3, gt4, gt5, gt6, gt7;
  unsigned rm0 = 0u, rm1 = 0u;
  sel_group<0>(prow, 0u, gv0, gt0);
  sel_group<1>(prow, 0u, gv1, gt1);
  sel_group<2>(prow, 0u, gv2, gt2);
  sel_group<3>(prow, 0u, gv3, gt3);
  sel_group<4>(prow, 0u, gv4, gt4);
  sel_group<5>(prow, 0u, gv5, gt5);
  sel_group<6>(prow, 0u, gv6, gt6);
  sel_group<7>(prow, 0u, gv7, gt7);
  float lv; int lt;
  LANE_SCAN();

  int myidx = 0;
  #pragma unroll 1
  for (int r = 0; r < KNN; ++r) {
    float m = wave_max_f32(lv);
    unsigned long long bal = __ballot(lv == m);
    int wl = (int)__builtin_ctzll(bal);
    int tsel = __builtin_amdgcn_readlane(lt, wl);
    if (lane == r) myidx = (wl << 6) | tsel;
    if (lane == wl) {
      switch (tsel >> 3) {
        case 0: rm0 |= 1u << (tsel & 7);        sel_group<0>(prow, rm0 & 0xffu,         gv0, gt0); break;
        case 1: rm0 |= 1u << (8 + (tsel & 7));  sel_group<1>(prow, (rm0 >> 8) & 0xffu,  gv1, gt1); break;
        case 2: rm0 |= 1u << (16 + (tsel & 7)); sel_group<2>(prow, (rm0 >> 16) & 0xffu, gv2, gt2); break;
        case 3: rm0 |= 1u << (24 + (tsel & 7)); sel_group<3>(prow, (rm0 >> 24) & 0xffu, gv3, gt3); break;
        case 4: rm1 |= 1u << (tsel & 7);        sel_group<4>(prow, rm1 & 0xffu,         gv4, gt4); break;
        case 5: rm1 |= 1u << (8 + (tsel & 7));  sel_group<5>(prow, (rm1 >> 8) & 0xffu,  gv5, gt5); break;
        case 6: rm1 |= 1u << (16 + (tsel & 7)); sel_group<6>(prow, (rm1 >> 16) & 0xffu, gv6, gt6); break;
        case 7: rm1 |= 1u << (24 + (tsel & 7)); sel_group<7>(prow, (rm1 >> 24) & 0xffu, gv7, gt7); break;
      }
      LANE_SCAN();
    }
  }
  if (lane < KNN) out[lane] = myidx;
}

// per-batch select (pd holds one batch)
__global__ __launch_bounds__(256) void knn_select_kernel(const float* __restrict__ pd,
                                                         int* __restrict__ idx2, int b) {
  int wave = threadIdx.x >> 6, lane = threadIdx.x & 63;
  int row = blockIdx.x * 4 + wave;
  select_row(pd + (size_t)row * NP + (lane << 6), lane,
             idx2 + (size_t)(b * NP + row) * KNN);
}

// all-batch select (pd8 holds all 8 batches) — full occupancy in one launch
__global__ __launch_bounds__(256) void knn_select_all_kernel(const float* __restrict__ pd8,
                                                             int* __restrict__ idx2) {
  int wave = threadIdx.x >> 6, lane = threadIdx.x & 63;
  int rowg = blockIdx.x * 4 + wave;     // 0..32767
  select_row(pd8 + (size_t)rowg * NP + (lane << 6), lane,
             idx2 + (size_t)rowg * KNN);
}

// ---------------------------------------------------------------------------
// F1[j] = mlp1(x[0,j])  (3->64 relu ->64 relu ->64), one wave per row
// ---------------------------------------------------------------------------
__global__ __launch_bounds__(256) void mlp1_kernel(const float* __restrict__ x,
                                                   const float* __restrict__ w1, const float* __restrict__ b1,
                                                   const float* __restrict__ w2, const float* __restrict__ b2,
                                                   const float* __restrict__ w3, const float* __restrict__ b3,
                                                   float* __restrict__ F1) {
  int wave = threadIdx.x >> 6, lane = threadIdx.x & 63;
  int j = blockIdx.x * 4 + wave;        // 0..4095 (batch 0 rows)
  float x0 = x[j * 3 + 0], x1 = x[j * 3 + 1], x2 = x[j * 3 + 2];
  float h1 = fmaf(x2, w1[128 + lane], fmaf(x1, w1[64 + lane], fmaf(x0, w1[lane], b1[lane])));
  h1 = fmaxf(h1, 0.f);
  float acc = b2[lane];
  #pragma unroll
  for (int c = 0; c < 64; ++c) acc = fmaf(__shfl(h1, c, 64), w2[c * 64 + lane], acc);
  float h2 = fmaxf(acc, 0.f);
  acc = b3[lane];
  #pragma unroll
  for (int c = 0; c < 64; ++c) acc = fmaf(__shfl(h2, c, 64), w3[c * 64 + lane], acc);
  F1[j * 64 + lane] = acc;
}

// ---------------------------------------------------------------------------
// h[row] = max_k F1[idx1[row,k]] ; sqh[row] = ||h[row]||^2
// ---------------------------------------------------------------------------
__global__ __launch_bounds__(256) void pool1_kernel(const float* __restrict__ F1,
                                                    const int* __restrict__ idx1,
                                                    float* __restrict__ h,
                                                    float* __restrict__ sqh) {
  int wave = threadIdx.x >> 6, lane = threadIdx.x & 63;
  int row = blockIdx.x * 4 + wave;
  float m = NEGF;
  #pragma unroll
  for (int k = 0; k < KNN; ++k) {
    int jj = idx1[(size_t)row * KNN + k];
    m = fmaxf(m, F1[jj * 64 + lane]);
  }
  h[(size_t)row * 64 + lane] = m;
  float s = m * m;
  #pragma unroll
  for (int off = 32; off; off >>= 1) s += __shfl_xor(s, off, 64);
  if (lane == 0) sqh[row] = s;
}

// ---------------------------------------------------------------------------
// pd[i][j] = 2*h_i.h_j - sq_i - sq_j (4096x4096x64 f32 GEMM per batch)
// ---------------------------------------------------------------------------
__device__ __forceinline__ int swz(int g, int r) { return g ^ ((r & 15) ^ ((r >> 4) & 3)); }

__device__ __forceinline__ void pd_tile(const float* __restrict__ hb,
                                        const float* __restrict__ sq,
                                        float* __restrict__ pdb,
                                        int it, int jt, int tid) {
  __shared__ float As[64 * 64];
  __shared__ float Bs[64 * 64];
  const int i0 = it * 64, j0 = jt * 64;
  #pragma unroll
  for (int s = 0; s < 4; ++s) {
    int f4 = tid + s * 256;
    int r = f4 >> 4, g = f4 & 15;
    int gs = swz(g, r);
    float4 va = *reinterpret_cast<const float4*>(&hb[(size_t)(i0 + r) * 64 + g * 4]);
    *reinterpret_cast<float4*>(&As[r * 64 + gs * 4]) = va;
    float4 vb = *reinterpret_cast<const float4*>(&hb[(size_t)(j0 + r) * 64 + g * 4]);
    *reinterpret_cast<float4*>(&Bs[r * 64 + gs * 4]) = vb;
  }
  __syncthreads();
  const int tx = tid & 15, ty = tid >> 4;
  float acc[4][4] = {};
  #pragma unroll
  for (int c = 0; c < 64; c += 4) {
    int g = c >> 2;
    float4 a[4], bb[4];
    #pragma unroll
    for (int q = 0; q < 4; ++q) {
      int r = ty * 4 + q;
      a[q] = *reinterpret_cast<const float4*>(&As[r * 64 + (swz(g, r) << 2)]);
    }
    #pragma unroll
    for (int p = 0; p < 4; ++p) {
      int r = tx * 4 + p;
      bb[p] = *reinterpret_cast<const float4*>(&Bs[r * 64 + (swz(g, r) << 2)]);
    }
    #pragma unroll
    for (int q = 0; q < 4; ++q) {
      #pragma unroll
      for (int p = 0; p < 4; ++p) {
        acc[q][p] = fmaf(a[q].x, bb[p].x, acc[q][p]);
        acc[q][p] = fmaf(a[q].y, bb[p].y, acc[q][p]);
        acc[q][p] = fmaf(a[q].z, bb[p].z, acc[q][p]);
        acc[q][p] = fmaf(a[q].w, bb[p].w, acc[q][p]);
      }
    }
  }
  float sj0 = sq[j0 + tx * 4 + 0];
  float sj1 = sq[j0 + tx * 4 + 1];
  float sj2 = sq[j0 + tx * 4 + 2];
  float sj3 = sq[j0 + tx * 4 + 3];
  #pragma unroll
  for (int q = 0; q < 4; ++q) {
    int i = i0 + ty * 4 + q;
    float sqi = sq[i];
    float4 o;
    o.x = 2.f * acc[q][0] - sqi - sj0;
    o.y = 2.f * acc[q][1] - sqi - sj1;
    o.z = 2.f * acc[q][2] - sqi - sj2;
    o.w = 2.f * acc[q][3] - sqi - sj3;
    *reinterpret_cast<float4*>(&pdb[(size_t)i * NP + j0 + tx * 4]) = o;
  }
}

__global__ __launch_bounds__(256) void pd_gemm_kernel(const float* __restrict__ h,
                                                      const float* __restrict__ sqh,
                                                      float* __restrict__ pd, int b) {
  pd_tile(h + (size_t)b * NP * 64, sqh + b * NP, pd,
          blockIdx.x >> 6, blockIdx.x & 63, threadIdx.x);
}

__global__ __launch_bounds__(256) void pd_gemm_all_kernel(const float* __restrict__ h,
                                                          const float* __restrict__ sqh,
                                                          float* __restrict__ pd8) {
  int b = blockIdx.x >> 12;
  int tile = blockIdx.x & 4095;
  pd_tile(h + (size_t)b * NP * 64, sqh + b * NP, pd8 + (size_t)b * NP * NP,
          tile >> 6, tile & 63, threadIdx.x);
}

// ---------------------------------------------------------------------------
// fallback fused knn2 (no pd buffer): full-rescan topk (normally unused)
// ---------------------------------------------------------------------------
__device__ __forceinline__ void clear_slot_fb(float (&val)[64], int tw, int lw, int lane) {
  switch (tw) {
#define CS(T) case T: if (lane == lw) val[T] = NEGF; break;
    CS(0) CS(1) CS(2) CS(3) CS(4) CS(5) CS(6) CS(7)
    CS(8) CS(9) CS(10) CS(11) CS(12) CS(13) CS(14) CS(15)
    CS(16) CS(17) CS(18) CS(19) CS(20) CS(21) CS(22) CS(23)
    CS(24) CS(25) CS(26) CS(27) CS(28) CS(29) CS(30) CS(31)
    CS(32) CS(33) CS(34) CS(35) CS(36) CS(37) CS(38) CS(39)
    CS(40) CS(41) CS(42) CS(43) CS(44) CS(45) CS(46) CS(47)
    CS(48) CS(49) CS(50) CS(51) CS(52) CS(53) CS(54) CS(55)
    CS(56) CS(57) CS(58) CS(59) CS(60) CS(61) CS(62) CS(63)
#undef CS
  }
}

__device__ __forceinline__ void wave_topk_fb(float (&val)[64], int lane, int rowbase,
                                             int* __restrict__ idx_out) {
  int myidx = 0;
  #pragma unroll 1
  for (int r = 0; r < KNN; ++r) {
    float m[4]; int mt[4];
    #pragma unroll
    for (int q = 0; q < 4; ++q) { m[q] = val[q]; mt[q] = q; }
    #pragma unroll
    for (int t = 4; t < 64; t += 4) {
      #pragma unroll
      for (int q = 0; q < 4; ++q) {
        if (val[t + q] > m[q]) { m[q] = val[t + q]; mt[q] = t + q; }
      }
    }
    if (m[1] > m[0] || (m[1] == m[0] && mt[1] < mt[0])) { m[0] = m[1]; mt[0] = mt[1]; }
    if (m[3] > m[2] || (m[3] == m[2] && mt[3] < mt[2])) { m[2] = m[3]; mt[2] = mt[3]; }
    if (m[2] > m[0] || (m[2] == m[0] && mt[2] < mt[0])) { m[0] = m[2]; mt[0] = mt[2]; }
    float mv = m[0];
    int mj = mt[0] * 64 + lane;
    #pragma unroll
    for (int off = 32; off; off >>= 1) {
      float om = __shfl_xor(mv, off, 64);
      int   oj = __shfl_xor(mj, off, 64);
      if (om > mv || (om == mv && oj < mj)) { mv = om; mj = oj; }
    }
    clear_slot_fb(val, mj >> 6, mj & 63, lane);
    if (lane == r) myidx = mj;
  }
  if (lane < KNN) idx_out[(size_t)rowbase * KNN + lane] = myidx;
}

__global__ __launch_bounds__(512) void knn2_fused_kernel(const float* __restrict__ h,
                                                         const float* __restrict__ sqh,
                                                         int* __restrict__ idx2) {
  __shared__ float tile[64 * 64];
  const int wave = threadIdx.x >> 6, lane = threadIdx.x & 63;
  const int row = blockIdx.x * 8 + wave;
  const int b = row >> 12;
  const int jb = b * NP;
  float hi[64];
  #pragma unroll
  for (int q2 = 0; q2 < 16; ++q2) {
    float4 v = *reinterpret_cast<const float4*>(&h[(size_t)row * 64 + q2 * 4]);
    hi[q2 * 4 + 0] = v.x; hi[q2 * 4 + 1] = v.y; hi[q2 * 4 + 2] = v.z; hi[q2 * 4 + 3] = v.w;
  }
  float sqi = sqh[row];
  float val[64];
  #pragma unroll
  for (int tt = 0; tt < 64; ++tt) {
    __syncthreads();
    #pragma unroll
    for (int s = 0; s < 2; ++s) {
      int f4 = threadIdx.x + s * 512;
      int jj = f4 >> 4, g = f4 & 15;
      float4 v = *reinterpret_cast<const float4*>(&h[(size_t)(jb + tt * 64 + jj) * 64 + g * 4]);
      int gs = g ^ (jj & 15);
      *reinterpret_cast<float4*>(&tile[jj * 64 + gs * 4]) = v;
    }
    __syncthreads();
    float acc = 0.f;
    #pragma unroll
    for (int g = 0; g < 16; ++g) {
      int gs = g ^ (lane & 15);
      float4 v = *reinterpret_cast<const float4*>(&tile[lane * 64 + gs * 4]);
      acc = fmaf(hi[4 * g + 0], v.x, acc);
      acc = fmaf(hi[4 * g + 1], v.y, acc);
      acc = fmaf(hi[4 * g + 2], v.z, acc);
      acc = fmaf(hi[4 * g + 3], v.w, acc);
    }
    val[tt] = 2.f * acc - sqi - sqh[jb + tt * 64 + lane];
  }
  wave_topk_fb(val, lane, row, idx2);
}

// ---------------------------------------------------------------------------
// G4[j] = h[0,j] @ w4 + b4  (64 -> 128)
// ---------------------------------------------------------------------------
__global__ __launch_bounds__(128) void g4_kernel(const float* __restrict__ h,
                                                 const float* __restrict__ w4,
                                                 const float* __restrict__ b4,
                                                 float* __restrict__ G4) {
  __shared__ float hj[64];
  int j = blockIdx.x;
  int o = threadIdx.x;
  if (o < 64) hj[o] = h[(size_t)j * 64 + o];
  __syncthreads();
  float acc = b4[o];
  #pragma unroll
  for (int c = 0; c < 64; ++c) acc = fmaf(hj[c], w4[c * 128 + o], acc);
  G4[(size_t)j * 128 + o] = acc;
}

// ---------------------------------------------------------------------------
// h2[row] = max_k G4[idx2[row,k]]
// ---------------------------------------------------------------------------
__global__ __launch_bounds__(256) void pool2_kernel(const float* __restrict__ G4,
                                                    const int* __restrict__ idx2,
                                                    float* __restrict__ h2) {
  int gid = blockIdx.x * 256 + threadIdx.x;
  int row = gid >> 7, o = gid & 127;
  float m = NEGF;
  #pragma unroll
  for (int k = 0; k < KNN; ++k) {
    int jj = idx2[(size_t)row * KNN + k];
    m = fmaxf(m, G4[(size_t)jj * 128 + o]);
  }
  h2[(size_t)gid] = m;
}

// ---------------------------------------------------------------------------
// out = h2 @ w5 + b5  (32768 x 1024 x 128), 64x64 tile, 4x4/thread
// ---------------------------------------------------------------------------
__global__ __launch_bounds__(256) void final_gemm_kernel(const float* __restrict__ h2,
                                                         const float* __restrict__ w5,
                                                         const float* __restrict__ b5,
                                                         float* __restrict__ out) {
  __shared__ float As[64 * 128];
  __shared__ float Bs[128 * 64];
  const int mt = blockIdx.x >> 4;
  const int nt = blockIdx.x & 15;
  const int row0 = mt * 64, col0 = nt * 64;
  const int tid = threadIdx.x;
  #pragma unroll
  for (int s = 0; s < 8; ++s) {
    int f4 = tid + s * 256;
    int i = f4 >> 5, kf = f4 & 31;
    float4 v = *reinterpret_cast<const float4*>(&h2[(size_t)(row0 + i) * 128 + kf * 4]);
    *reinterpret_cast<float4*>(&As[i * 128 + kf * 4]) = v;
  }
  #pragma unroll
  for (int s = 0; s < 8; ++s) {
    int f4 = tid + s * 256;
    int k = f4 >> 4, g = f4 & 15;
    float4 v = *reinterpret_cast<const float4*>(&w5[(size_t)k * 1024 + col0 + g * 4]);
    *reinterpret_cast<float4*>(&Bs[k * 64 + g * 4]) = v;
  }
  __syncthreads();
  const int tx = tid & 15, ty = tid >> 4;
  float acc[4][4] = {};
  #pragma unroll
  for (int k = 0; k < 128; k += 4) {
    float4 a[4], bb[4];
    #pragma unroll
    for (int q = 0; q < 4; ++q)
      a[q] = *reinterpret_cast<const float4*>(&As[(ty * 4 + q) * 128 + k]);
    #pragma unroll
    for (int kk = 0; kk < 4; ++kk)
      bb[kk] = *reinterpret_cast<const float4*>(&Bs[(k + kk) * 64 + tx * 4]);
    #pragma unroll
    for (int q = 0; q < 4; ++q) {
      acc[q][0] = fmaf(a[q].w, bb[3].x, fmaf(a[q].z, bb[2].x, fmaf(a[q].y, bb[1].x, fmaf(a[q].x, bb[0].x, acc[q][0]))));
      acc[q][1] = fmaf(a[q].w, bb[3].y, fmaf(a[q].z, bb[2].y, fmaf(a[q].y, bb[1].y, fmaf(a[q].x, bb[0].y, acc[q][1]))));
      acc[q][2] = fmaf(a[q].w, bb[3].z, fmaf(a[q].z, bb[2].z, fmaf(a[q].y, bb[1].z, fmaf(a[q].x, bb[0].z, acc[q][2]))));
      acc[q][3] = fmaf(a[q].w, bb[3].w, fmaf(a[q].z, bb[2].w, fmaf(a[q].y, bb[1].w, fmaf(a[q].x, bb[0].w, acc[q][3]))));
    }
  }
  float b0 = b5[col0 + tx * 4 + 0];
  float b1 = b5[col0 + tx * 4 + 1];
  float b2 = b5[col0 + tx * 4 + 2];
  float b3 = b5[col0 + tx * 4 + 3];
  #pragma unroll
  for (int q = 0; q < 4; ++q) {
    float4 o;
    o.x = acc[q][0] + b0;
    o.y = acc[q][1] + b1;
    o.z = acc[q][2] + b2;
    o.w = acc[q][3] + b3;
    *reinterpret_cast<float4*>(&out[(size_t)(row0 + ty * 4 + q) * 1024 + col0 + tx * 4]) = o;
  }
}

// ---------------------------------------------------------------------------
extern "C" void kernel_launch(void* const* d_in, const int* in_sizes, int n_in,
                              void* d_out, int out_size, void* d_ws, size_t ws_size,
                              hipStream_t stream) {
  const float* x  = (const float*)d_in[0];
  const float* w1 = (const float*)d_in[1];
  const float* b1 = (const float*)d_in[2];
  const float* w2 = (const float*)d_in[3];
  const float* b2 = (const float*)d_in[4];
  const float* w3 = (const float*)d_in[5];
  const float* b3 = (const float*)d_in[6];
  const float* w4 = (const float*)d_in[7];
  const float* b4 = (const float*)d_in[8];
  const float* w5 = (const float*)d_in[9];
  const float* b5 = (const float*)d_in[10];
  float* out = (float*)d_out;
  char* ws = (char*)d_ws;

  // layout (bytes)
  float* h    = (float*)(ws + 0);                       //  8,388,608
  float* sqh  = (float*)(ws + 8388608);                 //    131,072
  int*   idx2 = (int*)  (ws + 8519680);                 //  2,621,440
  char*  X    = ws + 11141120;                          // overlay region
  float* sqx  = (float*)(X + 0);                        //    131,072 (dead after knn1)
  int*   idx1 = (int*)  (X + 131072);                   //  2,621,440 (dead after pool1)
  float* F1   = (float*)(X + 2752512);                  //  1,048,576 (dead after pool1)
  float* pd   = (float*)(X + 0);                        // pd: 67MB/batch or 537MB all
  float* G4   = (float*)(X + 0);                        //  2,097,152 (after knn2)
  float* h2   = (float*)(X + 2097152);                  // 16,777,216 (after knn2)

  const size_t OVERLAY   = 11141120;
  const size_t NEED_FAST = OVERLAY + (size_t)NP * NP * 4;                 //  78 MB
  const size_t NEED_FULL = OVERLAY + (size_t)NBATCH * NP * NP * 4;        // 548 MB

  sq_kernel<<<128, 256, 0, stream>>>(x, sqx);
  knn1_kernel<<<8192, 256, 0, stream>>>(x, sqx, idx1);
  mlp1_kernel<<<1024, 256, 0, stream>>>(x, w1, b1, w2, b2, w3, b3, F1);
  pool1_kernel<<<8192, 256, 0, stream>>>(F1, idx1, h, sqh);

  if (ws_size >= NEED_FULL) {
    pd_gemm_all_kernel<<<32768, 256, 0, stream>>>(h, sqh, pd);
    knn_select_all_kernel<<<8192, 256, 0, stream>>>(pd, idx2);
  } else if (ws_size >= NEED_FAST) {
    for (int b = 0; b < NBATCH; ++b) {
      pd_gemm_kernel<<<4096, 256, 0, stream>>>(h, sqh, pd, b);
      knn_select_kernel<<<1024, 256, 0, stream>>>(pd, idx2, b);
    }
  } else {
    knn2_fused_kernel<<<4096, 512, 0, stream>>>(h, sqh, idx2);
  }

  g4_kernel<<<4096, 128, 0, stream>>>(h, w4, b4, G4);
  pool2_kernel<<<16384, 256, 0, stream>>>(G4, idx2, h2);
  final_gemm_kernel<<<8192, 256, 0, stream>>>(h2, w5, b5, out);
}